// Round 2
// baseline (1734.543 us; speedup 1.0000x reference)
//
#include <hip/hip_runtime.h>
#include <hip/hip_bf16.h>
#include <stdint.h>
#include <stddef.h>

typedef short v8s __attribute__((ext_vector_type(8)));
typedef float v4f __attribute__((ext_vector_type(4)));

#define STEPSZ 0.01f

/* workspace layout (bytes) */
#define OFF_ARE 0u        /* bf16 [2048][512] swizzled: 2 MB (B^T GEMM1) */
#define OFF_ATT 2097152u  /* bf16 [4096][256] swizzled: 2 MB (B^T GEMM2) */
#define OFF_XF  4194304u  /* f32  [512][512] : 1 MB  (x master) */
#define OFF_XB  5242880u  /* bf16 [512][512] : 512 KB (x operand) */
#define OFF_ERR 5767168u  /* bf16 [512][256] : 256 KB (err operand) */
#define OFF_YT  6029312u  /* f32  [512][256] : 512 KB (y transposed) */
#define OFF_BAR 6553600u  /* int  [512]      : 2 KB  (cluster barriers) */

__device__ __forceinline__ void async_lds16(const void* g, void* l) {
  __builtin_amdgcn_global_load_lds(
      (const __attribute__((address_space(1))) uint32_t*)g,
      (__attribute__((address_space(3))) uint32_t*)l, 16, 0, 0);
}

/* --- prep: build swizzled B operands. Within each 64-elem k-block of a row,
   element k is stored at ((k + (row&7)*8) & 63) so LDS frag reads are
   bank-conflict-free after the contiguity-constrained DMA staging. --- */
__global__ void prep_fwd(const float* __restrict__ A, __hip_bfloat16* __restrict__ AreT) {
  const int m = blockIdx.x;   // 256
  const int n = threadIdx.x;  // 512
  const float* ap = A + ((size_t)m * 512 + n) * 8;
  const int k0 = n & ~63, kin = n & 63;
#pragma unroll
  for (int j = 0; j < 8; ++j) {
    const int row = m * 8 + j;
    const int pos = k0 + ((kin + (row & 7) * 8) & 63);
    AreT[(size_t)row * 512 + pos] = __float2bfloat16(ap[j]);
  }
}

__global__ void prep_bwd(const float* __restrict__ A, __hip_bfloat16* __restrict__ AtT) {
  const int n = blockIdx.x;   // 512
  const int m = threadIdx.x;  // 256
  const float* ap = A + ((size_t)m * 512 + n) * 8;
  const float rev[8] = {1.f, 1.f, 1.f, -1.f, 1.f, -1.f, -1.f, -1.f};
  const int k0 = m & ~63, kin = m & 63;
#pragma unroll
  for (int j = 0; j < 8; ++j) {
    const int row = n * 8 + j;
    const int pos = k0 + ((kin + (row & 7) * 8) & 63);
    AtT[(size_t)row * 256 + pos] = __float2bfloat16(ap[j] * rev[j]);
  }
}

/* yT[(b*8+k)*256 + m] = y[(b*256+m)*8 + k] */
__global__ void prep_y(const float* __restrict__ y, float* __restrict__ yT) {
  const int r = blockIdx.x;   // 512
  const int m = threadIdx.x;  // 256
  yT[(size_t)r * 256 + m] = y[((size_t)(r >> 3) * 256 + m) * 8 + (r & 7)];
}

__global__ void zero_x(float* __restrict__ xf, __hip_bfloat16* __restrict__ xb,
                       int* __restrict__ bar) {
  const int idx = blockIdx.x * blockDim.x + threadIdx.x;  // 262144
  xf[idx] = 0.f;
  xb[idx] = __float2bfloat16(0.f);
  if (idx < 512) bar[idx] = 0;
}

/* out[b,n,k] = xf[(b*8+k)*512 + n] */
__global__ void finalize(const float* __restrict__ xf, float* __restrict__ out) {
  const int idx = blockIdx.x * blockDim.x + threadIdx.x;  // 262144
  const int k = idx & 7;
  const int n = (idx >> 3) & 511;
  const int b = idx >> 12;
  out[idx] = xf[((size_t)(b * 8 + k) << 9) | n];
}

/* monotonic 16-block cluster barrier (device-scope) */
__device__ __forceinline__ void cbar(int* bar, int target) {
  __syncthreads();
  if (threadIdx.x == 0) {
    __threadfence();
    atomicAdd(bar, 1);
    while (__hip_atomic_load(bar, __ATOMIC_RELAXED, __HIP_MEMORY_SCOPE_AGENT) < target)
      __builtin_amdgcn_s_sleep(2);
    __threadfence();
  }
  __syncthreads();
}

/* staging: chunk -> LDS, 4 rounds x 8KB, contiguous t*16B */
__device__ __forceinline__ void stage1(const __hip_bfloat16* Bg, __hip_bfloat16* buf,
                                       int ch, int tid, int wave) {
#pragma unroll
  for (int r = 0; r < 4; ++r)
    async_lds16(Bg + (size_t)(r * 32 + (tid >> 4)) * 512 + ch * 128 + (tid & 15) * 8,
                buf + r * 4096 + wave * 512);
}
__device__ __forceinline__ void stage2(const __hip_bfloat16* Bg, __hip_bfloat16* buf,
                                       int ch, int tid, int wave) {
#pragma unroll
  for (int r = 0; r < 4; ++r)
    async_lds16(Bg + (size_t)(r * 64 + (tid >> 3)) * 256 + ch * 64 + (tid & 7) * 8,
                buf + r * 4096 + wave * 512);
}
/* A-operand fragments direct from global (rows tiny, L2-hot) */
__device__ __forceinline__ void loadA1(v8s* d, const __hip_bfloat16* Ag, int ch,
                                       int rg, int fr, int fq) {
  const __hip_bfloat16* p = Ag + (size_t)(rg * 16 + fr) * 512 + ch * 128 + fq * 8;
#pragma unroll
  for (int s = 0; s < 4; ++s) d[s] = *(const v8s*)(p + s * 32);
}
__device__ __forceinline__ void loadA2(v8s* d, const __hip_bfloat16* Ag, int ch,
                                       int rg, int fr, int fq) {
  const __hip_bfloat16* p = Ag + (size_t)(rg * 16 + fr) * 256 + ch * 64 + fq * 8;
#pragma unroll
  for (int s = 0; s < 2; ++s) d[s] = *(const v8s*)(p + s * 32);
}

/* Persistent kernel: 256 blocks x 512 threads. Cluster = blockIdx%16 (16 blocks,
 * same XCD under %8 swizzle) owns 4 batches (32 GEMM rows) for all 50 iterations.
 * Member w = blockIdx/16 owns a column slice. 2 cluster barriers per iteration. */
__global__ __launch_bounds__(512, 2) void ista_persist(
    const __hip_bfloat16* __restrict__ AreT, const __hip_bfloat16* __restrict__ AtT,
    const float* __restrict__ yT, __hip_bfloat16* __restrict__ errb,
    float* __restrict__ xf, __hip_bfloat16* __restrict__ xb, int* __restrict__ bars) {
  __shared__ __align__(16) char arena[65536];
  __hip_bfloat16* buf0 = (__hip_bfloat16*)arena;
  __hip_bfloat16* buf1 = (__hip_bfloat16*)(arena + 32768);
  float* Pt = (float*)arena;

  const int tid = threadIdx.x;
  const int wave = tid >> 6, lane = tid & 63;
  const int fr = lane & 15, fq = lane >> 4;
  const int rg = wave >> 2, cg = wave & 3;  // 2x4 wave grid
  const int cl = blockIdx.x & 15, w = blockIdx.x >> 4;
  const int rowbase = cl * 32;  // 4 batches x 8 blades
  int* bar = bars + cl * 32;
  int ep = 0;

  const __hip_bfloat16* Bg1 = AreT + (size_t)(w * 128) * 512;  // 128 cols, K=512
  const __hip_bfloat16* Bg2 = AtT + (size_t)(w * 256) * 256;   // 256 cols, K=256
  const __hip_bfloat16* Ag1 = xb + (size_t)rowbase * 512;
  const __hip_bfloat16* Eg = errb + (size_t)rowbase * 256;

  for (int it = 0; it < 50; ++it) {
    /* ---------------- PHASE 1: err = recombine(x @ AreT^T) - y ---------------- */
    {
      v4f acc[2] = {};
      v8s curA[4], nxtA[4];
      stage1(Bg1, buf0, 0, tid, wave);
      loadA1(curA, Ag1, 0, rg, fr, fq);
      __syncthreads();
#pragma unroll
      for (int ch = 0; ch < 4; ++ch) {
        const __hip_bfloat16* rd = (ch & 1) ? buf1 : buf0;
        if (ch < 3) {
          stage1(Bg1, (ch & 1) ? buf0 : buf1, ch + 1, tid, wave);
          loadA1(nxtA, Ag1, ch + 1, rg, fr, fq);
        }
#pragma unroll
        for (int s = 0; s < 4; ++s) {
#pragma unroll
          for (int ct = 0; ct < 2; ++ct) {
            const int rl = cg * 32 + ct * 16 + fr;
            const v8s b = *(const v8s*)(rd + rl * 128 + (s >> 1) * 64 +
                                        (((s & 1) * 32 + fq * 8 + (rl & 7) * 8) & 63));
            acc[ct] = __builtin_amdgcn_mfma_f32_16x16x32_bf16(curA[s], b, acc[ct], 0, 0, 0);
          }
        }
        __syncthreads();
        if (ch < 3) {
#pragma unroll
          for (int s = 0; s < 4; ++s) curA[s] = nxtA[s];
        }
      }
#pragma unroll
      for (int ct = 0; ct < 2; ++ct)
#pragma unroll
        for (int v = 0; v < 4; ++v)
          Pt[(rg * 16 + fq * 4 + v) * 132 + cg * 32 + ct * 16 + fr] = acc[ct][v];
      __syncthreads();
      {
        const int ro = tid >> 4, ml = tid & 15;
        const int bl = ro >> 3, k = ro & 7;
        float s = 0.f;
#pragma unroll
        for (int j = 0; j < 8; ++j) {
          const int i = k ^ j;
          const int cnt = __popc((i >> 1) & j) + __popc((i >> 2) & j);
          const float p = Pt[(bl * 8 + i) * 132 + ml * 8 + j];
          s += (cnt & 1) ? -p : p;
        }
        const size_t eidx = (size_t)(rowbase + ro) * 256 + w * 16 + ml;
        errb[eidx] = __float2bfloat16(s - yT[eidx]);
      }
      cbar(bar, ++ep * 16);
    }
    /* ---------------- PHASE 2: grad = recombine(err @ AtT^T); x update -------- */
    {
      v4f acc[4] = {};
      v8s curA[2], nxtA[2];
      stage2(Bg2, buf0, 0, tid, wave);
      loadA2(curA, Eg, 0, rg, fr, fq);
      __syncthreads();
#pragma unroll
      for (int ch = 0; ch < 4; ++ch) {
        const __hip_bfloat16* rd = (ch & 1) ? buf1 : buf0;
        if (ch < 3) {
          stage2(Bg2, (ch & 1) ? buf0 : buf1, ch + 1, tid, wave);
          loadA2(nxtA, Eg, ch + 1, rg, fr, fq);
        }
#pragma unroll
        for (int s = 0; s < 2; ++s) {
#pragma unroll
          for (int ct = 0; ct < 4; ++ct) {
            const int rl = cg * 64 + ct * 16 + fr;
            const v8s b = *(const v8s*)(rd + rl * 64 +
                                        ((s * 32 + fq * 8 + (rl & 7) * 8) & 63));
            acc[ct] = __builtin_amdgcn_mfma_f32_16x16x32_bf16(curA[s], b, acc[ct], 0, 0, 0);
          }
        }
        __syncthreads();
        if (ch < 3) { curA[0] = nxtA[0]; curA[1] = nxtA[1]; }
      }
#pragma unroll
      for (int ct = 0; ct < 4; ++ct)
#pragma unroll
        for (int v = 0; v < 4; ++v)
          Pt[(rg * 16 + fq * 4 + v) * 260 + cg * 64 + ct * 16 + fr] = acc[ct][v];
      __syncthreads();
#pragma unroll
      for (int h = 0; h < 2; ++h) {
        const int o = tid + h * 512;
        const int ro = o >> 5, nl = o & 31;
        const int bl = ro >> 3, k = ro & 7;
        float s = 0.f;
#pragma unroll
        for (int j = 0; j < 8; ++j) {
          const int i = k ^ j;
          const int cnt = __popc((i >> 1) & j) + __popc((i >> 2) & j);
          const float p = Pt[(bl * 8 + i) * 260 + nl * 8 + j];
          s += (cnt & 1) ? -p : p;
        }
        const size_t idx = (size_t)(rowbase + ro) * 512 + w * 32 + nl;
        float xv = xf[idx] - STEPSZ * s;
        const float thr = (k == 0) ? 0.f : ((k == 7) ? 0.002f : 0.001f);
        const float ax = fabsf(xv) - thr;
        xv = (ax > 0.f) ? copysignf(ax, xv) : 0.f;
        xf[idx] = xv;
        xb[idx] = __float2bfloat16(xv);
      }
      if (it < 49) cbar(bar, ++ep * 16);
    }
  }
}

extern "C" void kernel_launch(void* const* d_in, const int* in_sizes, int n_in,
                              void* d_out, int out_size, void* d_ws, size_t ws_size,
                              hipStream_t stream) {
  (void)in_sizes; (void)n_in; (void)out_size; (void)ws_size;
  const float* y = (const float*)d_in[0];
  const float* A = (const float*)d_in[1];
  float* out = (float*)d_out;
  char* ws = (char*)d_ws;

  __hip_bfloat16* AreT = (__hip_bfloat16*)(ws + OFF_ARE);
  __hip_bfloat16* AtT = (__hip_bfloat16*)(ws + OFF_ATT);
  float* xf = (float*)(ws + OFF_XF);
  __hip_bfloat16* xb = (__hip_bfloat16*)(ws + OFF_XB);
  __hip_bfloat16* errb = (__hip_bfloat16*)(ws + OFF_ERR);
  float* yT = (float*)(ws + OFF_YT);
  int* bars = (int*)(ws + OFF_BAR);

  prep_fwd<<<256, 512, 0, stream>>>(A, AreT);
  prep_bwd<<<512, 256, 0, stream>>>(A, AtT);
  prep_y<<<512, 256, 0, stream>>>(y, yT);
  zero_x<<<1024, 256, 0, stream>>>(xf, xb, bars);

  ista_persist<<<256, 512, 0, stream>>>(AreT, AtT, yT, errb, xf, xb, bars);

  finalize<<<1024, 256, 0, stream>>>(xf, out);
}